// Round 5
// baseline (260.333 us; speedup 1.0000x reference)
//
#include <hip/hip_runtime.h>

// MMD loss, N=4096 per side, D=256, fp32.
// R5: split-bf16 MFMA Gram (hh+hl+lh, ll dropped ~2^-18 rel), one-shot
//     fp32->(hi,lo) pre-pass. k_pairs: DOUBLE-BUFFERED global_load_lds
//     (64 KB LDS, single barrier per k-step; DMA for buf[i+1] issued right
//     after the barrier so it lands during compute on buf[i]) — fixes R4's
//     latency-bound serialization (MfmaUtil 10%, both pipes idle).
//     Granule-major LDS [g][row] in 16B units: DMA dst = base+lane*16 (HW
//     constraint) and frag ds_read_b128 conflict-free (measured 0).
//     k_conv fuses rowsq+colsum (per-block partials, no atomics).

#define NROWS 8192
#define HALF  4096
#define DIM   256
#define BM    128
#define BK    32          // = MFMA K; 4 granules of 8 bf16 per row
#define CONVB 128         // k_conv blocks; 64 rows each

typedef __bf16 bf16x8 __attribute__((ext_vector_type(8)));
typedef float f32x4 __attribute__((ext_vector_type(4)));
typedef unsigned short ushort8 __attribute__((ext_vector_type(8)));

__device__ __forceinline__ const float* row_ptr(const float* src, const float* tgt, int r) {
    return (r < HALF) ? (src + (size_t)r * DIM) : (tgt + (size_t)(r - HALF) * DIM);
}

__device__ __forceinline__ unsigned short bf16_rne(float x) {
    unsigned int u = __builtin_bit_cast(unsigned int, x);
    return (unsigned short)((u + 0x7FFFu + ((u >> 16) & 1u)) >> 16);
}

__device__ __forceinline__ void gl2lds16(const void* g, void* l) {
    __builtin_amdgcn_global_load_lds(
        (const __attribute__((address_space(1))) unsigned int*)g,
        (__attribute__((address_space(3))) unsigned int*)l, 16, 0, 0);
}

// --- Phase 0: fp32 -> hi/lo planes + sq[] + per-block colsum partials ---
__global__ __launch_bounds__(256) void k_conv(const float* __restrict__ src,
                                              const float* __restrict__ tgt,
                                              unsigned short* __restrict__ hi,
                                              unsigned short* __restrict__ lo,
                                              float* __restrict__ sq,
                                              float* __restrict__ part,
                                              double* __restrict__ accum) {
    int w = threadIdx.x >> 6, lane = threadIdx.x & 63;
    int r0 = blockIdx.x * 64 + w * 16;
    float4 csum = {0.f, 0.f, 0.f, 0.f};
    for (int i = 0; i < 16; ++i) {
        int row = r0 + i;
        const float* rp = row_ptr(src, tgt, row);
        float4 v = ((const float4*)rp)[lane];       // 64 lanes * 4 floats = 256
        float xs[4] = {v.x, v.y, v.z, v.w};
        unsigned short hs[4], ls[4];
        #pragma unroll
        for (int j = 0; j < 4; ++j) {
            unsigned short hh = bf16_rne(xs[j]);
            float hr = __builtin_bit_cast(float, (unsigned int)hh << 16);
            hs[j] = hh;
            ls[j] = bf16_rne(xs[j] - hr);
        }
        ushort4 h4 = {hs[0], hs[1], hs[2], hs[3]};
        ushort4 l4 = {ls[0], ls[1], ls[2], ls[3]};
        ((ushort4*)(hi + (size_t)row * DIM))[lane] = h4;
        ((ushort4*)(lo + (size_t)row * DIM))[lane] = l4;
        csum.x += v.x; csum.y += v.y; csum.z += v.z; csum.w += v.w;
        float s = v.x * v.x + v.y * v.y + v.z * v.z + v.w * v.w;
        #pragma unroll
        for (int off = 32; off; off >>= 1) s += __shfl_xor(s, off, 64);
        if (lane == 0) sq[row] = s;
    }
    __shared__ float4 cs[4][64];
    cs[w][lane] = csum;
    __syncthreads();
    if (w == 0) {
        float4 a = cs[0][lane], b = cs[1][lane], c = cs[2][lane], d = cs[3][lane];
        float4 tot = {a.x + b.x + c.x + d.x, a.y + b.y + c.y + d.y,
                      a.z + b.z + c.z + d.z, a.w + b.w + c.w + d.w};
        *(float4*)&part[(size_t)blockIdx.x * DIM + lane * 4] = tot;
    }
    if (blockIdx.x == 0 && threadIdx.x == 0) *accum = 0.0;
}

// --- Phase 1: bandwidth -> exp2 scale factor ---
__global__ __launch_bounds__(256) void k_scale(const float* __restrict__ sq,
                                               const float* __restrict__ part,
                                               float* __restrict__ scale) {
    __shared__ double sh[256];
    int t = threadIdx.x;
    double s1 = 0.0;
    for (int i = t; i < NROWS; i += 256) s1 += (double)sq[i];
    sh[t] = s1;
    __syncthreads();
    for (int off = 128; off; off >>= 1) {
        if (t < off) sh[t] += sh[t + off];
        __syncthreads();
    }
    double S1 = sh[0];
    __syncthreads();
    float c = 0.0f;
    for (int b = 0; b < CONVB; ++b) c += part[b * DIM + t];  // coalesced
    sh[t] = (double)c * (double)c;
    __syncthreads();
    for (int off = 128; off; off >>= 1) {
        if (t < off) sh[t] += sh[t + off];
        __syncthreads();
    }
    if (t == 0) {
        double S2    = sh[0];
        double n     = (double)NROWS;
        double sumL2 = 2.0 * n * S1 - 2.0 * S2;
        double bw    = sumL2 / (n * n - n) / 4.0;   // / KERNEL_MUL^(KERNEL_NUM//2)
        // u = exp(-L2/(16*bw)) = exp2(scale * L2)
        *scale = (float)(-1.0 / (16.0 * bw * 0.69314718055994530942));
    }
}

// --- Phase 2: split-bf16 MFMA pair-tile kernel, double-buffered DMA ---
__global__ __launch_bounds__(256, 2) void k_pairs(const unsigned short* __restrict__ hi,
                                                  const unsigned short* __restrict__ lo,
                                                  const float* __restrict__ sq,
                                                  const float* __restrict__ scale_p,
                                                  double* __restrict__ accum) {
    int bi = blockIdx.y, bj = blockIdx.x;
    if (bj < bi) return;                            // upper-triangular tiles only

    // Granule-major per buffer: (row r, granule g) at ushort offset g*1024 + r*8.
    __shared__ __align__(16) unsigned short AsH[2][BM * BK];
    __shared__ __align__(16) unsigned short AsL[2][BM * BK];
    __shared__ __align__(16) unsigned short BsH[2][BM * BK];
    __shared__ __align__(16) unsigned short BsL[2][BM * BK];
    __shared__ float wsum[4];

    int t    = threadIdx.x;
    int lane = t & 63;
    int w    = t >> 6;
    int wr   = w >> 1, wc = w & 1;                  // 2x2 wave grid, 64x64 each
    int lr   = lane & 15, lq = lane >> 4;
    int ro = bi * BM, co = bj * BM;

    // Staging: wave w owns one plane: 0->A.hi 1->A.lo 2->B.hi 3->B.lo
    const unsigned short* gbase = (w & 1) ? lo : hi;
    int rowoff = (w < 2) ? ro : co;
    const unsigned short* gsrc = gbase + (size_t)(rowoff + lane) * DIM;
    unsigned short* lb0 = (w == 0) ? AsH[0] : (w == 1) ? AsL[0] : (w == 2) ? BsH[0] : BsL[0];
    unsigned short* lb1 = (w == 0) ? AsH[1] : (w == 1) ? AsL[1] : (w == 2) ? BsH[1] : BsL[1];

    f32x4 acc[4][4];
    #pragma unroll
    for (int m = 0; m < 4; ++m)
        #pragma unroll
        for (int n = 0; n < 4; ++n) acc[m][n] = (f32x4){0.f, 0.f, 0.f, 0.f};

    // Prologue: DMA k-chunk 0 into buffer 0
    #pragma unroll
    for (int g = 0; g < 4; ++g)
        #pragma unroll
        for (int h = 0; h < 2; ++h)
            gl2lds16(gsrc + (size_t)h * 64 * DIM + g * 8, lb0 + g * 1024 + h * 512);

    #pragma unroll
    for (int it = 0; it < DIM / BK; ++it) {
        // Single barrier: (a) all waves' prev-iter ds_reads drained (lgkm),
        // (b) this wave's DMA into buf[it&1] drained (vmcnt) — issued a full
        // compute phase ago, so the wait is near-zero.
        __syncthreads();
        if (it + 1 < DIM / BK) {                    // prefetch next chunk into other buf
            unsigned short* lb = ((it + 1) & 1) ? lb1 : lb0;
            int kk = (it + 1) * BK;
            #pragma unroll
            for (int g = 0; g < 4; ++g)
                #pragma unroll
                for (int h = 0; h < 2; ++h)
                    gl2lds16(gsrc + (size_t)h * 64 * DIM + kk + g * 8, lb + g * 1024 + h * 512);
        }

        const unsigned short* aH_ = AsH[it & 1];
        const unsigned short* aL_ = AsL[it & 1];
        const unsigned short* bH_ = BsH[it & 1];
        const unsigned short* bL_ = BsL[it & 1];
        bf16x8 aH[4], aL[4], bH[4], bL[4];
        #pragma unroll
        for (int m = 0; m < 4; ++m) {
            int off = lq * 1024 + (wr * 64 + m * 16 + lr) * 8;
            aH[m] = __builtin_bit_cast(bf16x8, *(const ushort8*)&aH_[off]);
            aL[m] = __builtin_bit_cast(bf16x8, *(const ushort8*)&aL_[off]);
        }
        #pragma unroll
        for (int n = 0; n < 4; ++n) {
            int off = lq * 1024 + (wc * 64 + n * 16 + lr) * 8;
            bH[n] = __builtin_bit_cast(bf16x8, *(const ushort8*)&bH_[off]);
            bL[n] = __builtin_bit_cast(bf16x8, *(const ushort8*)&bL_[off]);
        }
        #pragma unroll
        for (int m = 0; m < 4; ++m)
            #pragma unroll
            for (int n = 0; n < 4; ++n) {
                acc[m][n] = __builtin_amdgcn_mfma_f32_16x16x32_bf16(aH[m], bH[n], acc[m][n], 0, 0, 0);
                acc[m][n] = __builtin_amdgcn_mfma_f32_16x16x32_bf16(aH[m], bL[n], acc[m][n], 0, 0, 0);
                acc[m][n] = __builtin_amdgcn_mfma_f32_16x16x32_bf16(aL[m], bH[n], acc[m][n], 0, 0, 0);
                // lo*lo pass dropped: ~2^-18 relative on Gram term
            }
    }

    // ---- epilogue: L2 -> sum of 5 Gaussian kernels -> reduce
    float scale = *scale_p;
    int ro_eff = ro + wr * 64, co_eff = co + wc * 64;
    float4 sqa4[4];
    float  sqbv[4];
    #pragma unroll
    for (int m = 0; m < 4; ++m) sqa4[m] = *(const float4*)&sq[ro_eff + m * 16 + lq * 4];
    #pragma unroll
    for (int n = 0; n < 4; ++n) sqbv[n] = sq[co_eff + n * 16 + lr];

    float tsum = 0.0f;
    #pragma unroll
    for (int m = 0; m < 4; ++m) {
        float sa[4] = {sqa4[m].x, sqa4[m].y, sqa4[m].z, sqa4[m].w};
        #pragma unroll
        for (int n = 0; n < 4; ++n) {
            #pragma unroll
            for (int r = 0; r < 4; ++r) {
                float L2  = sa[r] + sqbv[n] - 2.0f * acc[m][n][r];
                float u   = __builtin_amdgcn_exp2f(scale * L2);
                float u2  = u * u;
                float u4  = u2 * u2;
                float u8  = u4 * u4;
                float u16 = u8 * u8;
                tsum += u + u2 + u4 + u8 + u16;     // 5 kernel scales
            }
        }
    }

    #pragma unroll
    for (int off = 32; off; off >>= 1) tsum += __shfl_xor(tsum, off, 64);
    if (lane == 0) wsum[w] = tsum;
    __syncthreads();
    if (t == 0) {
        float tot = wsum[0] + wsum[1] + wsum[2] + wsum[3];
        float sgn = ((ro < HALF) == (co < HALF)) ? 1.0f : -1.0f;
        float wgt = (bi == bj) ? 1.0f : 2.0f;       // off-diag tiles stand for (i,j)+(j,i)
        atomicAdd(accum, (double)(sgn * wgt * tot));
    }
}

// --- Finalize: mean normalization ---
__global__ void k_fin(const double* __restrict__ accum, float* __restrict__ out) {
    out[0] = (float)(*accum / ((double)HALF * (double)HALF));
}

extern "C" void kernel_launch(void* const* d_in, const int* in_sizes, int n_in,
                              void* d_out, int out_size, void* d_ws, size_t ws_size,
                              hipStream_t stream) {
    const float* src = (const float*)d_in[0];
    const float* tgt = (const float*)d_in[1];
    float* out = (float*)d_out;

    char* ws = (char*)d_ws;
    double* accum = (double*)ws;                                 // 8 B
    float*  scale = (float*)(ws + 16);                           // 4 B
    float*  sq    = (float*)(ws + 64);                           // 32768 B
    float*  part  = (float*)(ws + 64 + 32768);                   // 128*256*4 = 131072 B
    unsigned short* hi = (unsigned short*)(ws + 163904);         // 4 MB, 16B-aligned
    unsigned short* lo = (unsigned short*)(ws + 163904 + (size_t)NROWS * DIM * 2);

    k_conv <<<CONVB, 256, 0, stream>>>(src, tgt, hi, lo, sq, part, accum);
    k_scale<<<1, 256, 0, stream>>>(sq, part, scale);
    k_pairs<<<dim3(NROWS / BM, NROWS / BM), 256, 0, stream>>>(hi, lo, sq, scale, accum);
    k_fin  <<<1, 1, 0, stream>>>(accum, out);
}

// Round 6
// 148.747 us; speedup vs baseline: 1.7502x; 1.7502x over previous
//
#include <hip/hip_runtime.h>

// MMD loss, N=4096 per side, D=256, fp32.
// R6: split-bf16 MFMA Gram (hh+hl+lh; ll dropped, ~2^-18 rel).
//     KEY FIX vs R5: hi/lo planes stored in DMA-native tiled layout
//     plane[panel of 128 rows][granule g (8 bf16)][row r in panel] so each
//     global_load_lds reads 64 lanes x 16 B CONTIGUOUS (R5's row-major gather
//     caused 8x L2 over-read -> latency-bound, MfmaUtil 11%).
//     k_pairs: double-buffered DMA staging (one barrier/k-step), granule-major
//     LDS [g][row] (frag ds_read_b128 measured conflict-free).
//     k_conv: coalesced fp32 reads -> LDS transpose -> coalesced tiled writes,
//     fused with sq[] and colsum partials. Bandwidth scale exact fp32.

#define NROWS 8192
#define HALF  4096
#define DIM   256
#define BM    128
#define BK    32          // = MFMA K; 4 granules of 8 bf16 per row
#define CONVB 128         // k_conv blocks; 64 rows each (half a panel)

typedef __bf16 bf16x8 __attribute__((ext_vector_type(8)));
typedef float f32x4 __attribute__((ext_vector_type(4)));
typedef unsigned short ushort8 __attribute__((ext_vector_type(8)));

__device__ __forceinline__ const float* row_ptr(const float* src, const float* tgt, int r) {
    return (r < HALF) ? (src + (size_t)r * DIM) : (tgt + (size_t)(r - HALF) * DIM);
}

__device__ __forceinline__ unsigned short bf16_rne(float x) {
    unsigned int u = __builtin_bit_cast(unsigned int, x);
    return (unsigned short)((u + 0x7FFFu + ((u >> 16) & 1u)) >> 16);
}

__device__ __forceinline__ void gl2lds16(const void* g, void* l) {
    __builtin_amdgcn_global_load_lds(
        (const __attribute__((address_space(1))) unsigned int*)g,
        (__attribute__((address_space(3))) unsigned int*)l, 16, 0, 0);
}

// --- Phase 0: fp32 -> hi/lo planes (tiled layout) + sq[] + colsum partials ---
// Tiled plane layout: ushort offset of (global row R, granule g) =
//   ((R>>7)*32 + g)*128*8 + (R&127)*8      [panel-major, granule-major inside]
__global__ __launch_bounds__(256) void k_conv(const float* __restrict__ src,
                                              const float* __restrict__ tgt,
                                              unsigned short* __restrict__ hi,
                                              unsigned short* __restrict__ lo,
                                              float* __restrict__ sq,
                                              float* __restrict__ part,
                                              double* __restrict__ accum) {
    // LDS: granule-major for this block's 64 rows: (g*64 + r)*8
    __shared__ __align__(16) unsigned short sh_hi[32 * 64 * 8];  // 32 KB
    __shared__ __align__(16) unsigned short sh_lo[32 * 64 * 8];  // 32 KB
    __shared__ float4 cs[4][64];

    int w = threadIdx.x >> 6, lane = threadIdx.x & 63;
    int r0 = blockIdx.x * 64;                       // 64 rows per block
    int g  = lane >> 1, j = lane & 1;               // this lane's float4 = half-granule
    float4 csum = {0.f, 0.f, 0.f, 0.f};
    for (int i = 0; i < 16; ++i) {
        int rl  = w * 16 + i;                       // local row 0..63
        int row = r0 + rl;
        const float* rp = row_ptr(src, tgt, row);
        float4 v = ((const float4*)rp)[lane];       // coalesced: 64 lanes * 16 B
        float xs[4] = {v.x, v.y, v.z, v.w};
        unsigned short hs[4], ls[4];
        #pragma unroll
        for (int k = 0; k < 4; ++k) {
            unsigned short hh = bf16_rne(xs[k]);
            float hr = __builtin_bit_cast(float, (unsigned int)hh << 16);
            hs[k] = hh;
            ls[k] = bf16_rne(xs[k] - hr);
        }
        ushort4 h4 = {hs[0], hs[1], hs[2], hs[3]};
        ushort4 l4 = {ls[0], ls[1], ls[2], ls[3]};
        int so = (g * 64 + rl) * 8 + j * 4;
        *(ushort4*)&sh_hi[so] = h4;
        *(ushort4*)&sh_lo[so] = l4;
        csum.x += v.x; csum.y += v.y; csum.z += v.z; csum.w += v.w;
        float s = v.x * v.x + v.y * v.y + v.z * v.z + v.w * v.w;
        #pragma unroll
        for (int off = 32; off; off >>= 1) s += __shfl_xor(s, off, 64);
        if (lane == 0) sq[row] = s;
    }
    __syncthreads();
    // Coalesced tiled write-out: 2048 chunks of 16 B per plane.
    int panel = blockIdx.x >> 1, half = blockIdx.x & 1;
    #pragma unroll
    for (int c = threadIdx.x; c < 2048; c += 256) {
        int gg = c >> 6, r = c & 63;
        size_t goff = (((size_t)panel * 32 + gg) * 128 + half * 64 + r) * 8;
        *(ushort8*)&hi[goff] = *(const ushort8*)&sh_hi[c * 8];
        *(ushort8*)&lo[goff] = *(const ushort8*)&sh_lo[c * 8];
    }
    // colsum partials
    cs[w][lane] = csum;
    __syncthreads();
    if (w == 0) {
        float4 a = cs[0][lane], b = cs[1][lane], c = cs[2][lane], d = cs[3][lane];
        float4 tot = {a.x + b.x + c.x + d.x, a.y + b.y + c.y + d.y,
                      a.z + b.z + c.z + d.z, a.w + b.w + c.w + d.w};
        *(float4*)&part[(size_t)blockIdx.x * DIM + lane * 4] = tot;
    }
    if (blockIdx.x == 0 && threadIdx.x == 0) *accum = 0.0;
}

// --- Phase 1: bandwidth -> exp2 scale factor ---
__global__ __launch_bounds__(256) void k_scale(const float* __restrict__ sq,
                                               const float* __restrict__ part,
                                               float* __restrict__ scale) {
    __shared__ double sh[256];
    int t = threadIdx.x;
    double s1 = 0.0;
    for (int i = t; i < NROWS; i += 256) s1 += (double)sq[i];
    sh[t] = s1;
    __syncthreads();
    for (int off = 128; off; off >>= 1) {
        if (t < off) sh[t] += sh[t + off];
        __syncthreads();
    }
    double S1 = sh[0];
    __syncthreads();
    float c = 0.0f;
    for (int b = 0; b < CONVB; ++b) c += part[b * DIM + t];  // coalesced
    sh[t] = (double)c * (double)c;
    __syncthreads();
    for (int off = 128; off; off >>= 1) {
        if (t < off) sh[t] += sh[t + off];
        __syncthreads();
    }
    if (t == 0) {
        double S2    = sh[0];
        double n     = (double)NROWS;
        double sumL2 = 2.0 * n * S1 - 2.0 * S2;
        double bw    = sumL2 / (n * n - n) / 4.0;   // / KERNEL_MUL^(KERNEL_NUM//2)
        // u = exp(-L2/(16*bw)) = exp2(scale * L2)
        *scale = (float)(-1.0 / (16.0 * bw * 0.69314718055994530942));
    }
}

// --- Phase 2: split-bf16 MFMA pair-tile kernel, double-buffered coalesced DMA ---
__global__ __launch_bounds__(256, 2) void k_pairs(const unsigned short* __restrict__ hi,
                                                  const unsigned short* __restrict__ lo,
                                                  const float* __restrict__ sq,
                                                  const float* __restrict__ scale_p,
                                                  double* __restrict__ accum) {
    int bi = blockIdx.y, bj = blockIdx.x;
    if (bj < bi) return;                            // upper-triangular tiles only

    // Granule-major per buffer: (row r, granule g) at ushort offset g*1024 + r*8.
    __shared__ __align__(16) unsigned short AsH[2][BM * BK];
    __shared__ __align__(16) unsigned short AsL[2][BM * BK];
    __shared__ __align__(16) unsigned short BsH[2][BM * BK];
    __shared__ __align__(16) unsigned short BsL[2][BM * BK];
    __shared__ float wsum[4];

    int t    = threadIdx.x;
    int lane = t & 63;
    int w    = t >> 6;
    int wr   = w >> 1, wc = w & 1;                  // 2x2 wave grid, 64x64 each
    int lr   = lane & 15, lq = lane >> 4;
    int ro = bi * BM, co = bj * BM;

    // Staging: wave w owns one plane: 0->A.hi 1->A.lo 2->B.hi 3->B.lo
    const unsigned short* gbase = (w & 1) ? lo : hi;
    int panel = (w < 2) ? bi : bj;
    // Panel base; per (granule G, half h): + (G*128 + h*64 + lane)*8  (contiguous!)
    const unsigned short* gpanel = gbase + (size_t)panel * 32 * 128 * 8 + lane * 8;
    unsigned short* lb0 = (w == 0) ? AsH[0] : (w == 1) ? AsL[0] : (w == 2) ? BsH[0] : BsL[0];
    unsigned short* lb1 = (w == 0) ? AsH[1] : (w == 1) ? AsL[1] : (w == 2) ? BsH[1] : BsL[1];

    f32x4 acc[4][4];
    #pragma unroll
    for (int m = 0; m < 4; ++m)
        #pragma unroll
        for (int n = 0; n < 4; ++n) acc[m][n] = (f32x4){0.f, 0.f, 0.f, 0.f};

    // Prologue: DMA k-chunk 0 into buffer 0
    #pragma unroll
    for (int g = 0; g < 4; ++g)
        #pragma unroll
        for (int h = 0; h < 2; ++h)
            gl2lds16(gpanel + (g * 128 + h * 64) * 8, lb0 + g * 1024 + h * 512);

    #pragma unroll
    for (int it = 0; it < DIM / BK; ++it) {
        // Barrier drains: prev frag reads (lgkm) + this buf's DMA (vmcnt),
        // the latter issued a full compute phase ago.
        __syncthreads();
        if (it + 1 < DIM / BK) {                    // prefetch next chunk into other buf
            unsigned short* lb = ((it + 1) & 1) ? lb1 : lb0;
            #pragma unroll
            for (int g = 0; g < 4; ++g)
                #pragma unroll
                for (int h = 0; h < 2; ++h)
                    gl2lds16(gpanel + (((it + 1) * 4 + g) * 128 + h * 64) * 8,
                             lb + g * 1024 + h * 512);
        }

        const unsigned short* aH_ = AsH[it & 1];
        const unsigned short* aL_ = AsL[it & 1];
        const unsigned short* bH_ = BsH[it & 1];
        const unsigned short* bL_ = BsL[it & 1];
        bf16x8 aH[4], aL[4], bH[4], bL[4];
        #pragma unroll
        for (int m = 0; m < 4; ++m) {
            int off = lq * 1024 + (wr * 64 + m * 16 + lr) * 8;
            aH[m] = __builtin_bit_cast(bf16x8, *(const ushort8*)&aH_[off]);
            aL[m] = __builtin_bit_cast(bf16x8, *(const ushort8*)&aL_[off]);
        }
        #pragma unroll
        for (int n = 0; n < 4; ++n) {
            int off = lq * 1024 + (wc * 64 + n * 16 + lr) * 8;
            bH[n] = __builtin_bit_cast(bf16x8, *(const ushort8*)&bH_[off]);
            bL[n] = __builtin_bit_cast(bf16x8, *(const ushort8*)&bL_[off]);
        }
        #pragma unroll
        for (int m = 0; m < 4; ++m)
            #pragma unroll
            for (int n = 0; n < 4; ++n) {
                acc[m][n] = __builtin_amdgcn_mfma_f32_16x16x32_bf16(aH[m], bH[n], acc[m][n], 0, 0, 0);
                acc[m][n] = __builtin_amdgcn_mfma_f32_16x16x32_bf16(aH[m], bL[n], acc[m][n], 0, 0, 0);
                acc[m][n] = __builtin_amdgcn_mfma_f32_16x16x32_bf16(aL[m], bH[n], acc[m][n], 0, 0, 0);
                // lo*lo pass dropped: ~2^-18 relative on Gram term
            }
    }

    // ---- epilogue: L2 -> sum of 5 Gaussian kernels -> reduce
    float scale = *scale_p;
    int ro_eff = ro + wr * 64, co_eff = co + wc * 64;
    float4 sqa4[4];
    float  sqbv[4];
    #pragma unroll
    for (int m = 0; m < 4; ++m) sqa4[m] = *(const float4*)&sq[ro_eff + m * 16 + lq * 4];
    #pragma unroll
    for (int n = 0; n < 4; ++n) sqbv[n] = sq[co_eff + n * 16 + lr];

    float tsum = 0.0f;
    #pragma unroll
    for (int m = 0; m < 4; ++m) {
        float sa[4] = {sqa4[m].x, sqa4[m].y, sqa4[m].z, sqa4[m].w};
        #pragma unroll
        for (int n = 0; n < 4; ++n) {
            #pragma unroll
            for (int r = 0; r < 4; ++r) {
                float L2  = sa[r] + sqbv[n] - 2.0f * acc[m][n][r];
                float u   = __builtin_amdgcn_exp2f(scale * L2);
                float u2  = u * u;
                float u4  = u2 * u2;
                float u8  = u4 * u4;
                float u16 = u8 * u8;
                tsum += u + u2 + u4 + u8 + u16;     // 5 kernel scales
            }
        }
    }

    #pragma unroll
    for (int off = 32; off; off >>= 1) tsum += __shfl_xor(tsum, off, 64);
    if (lane == 0) wsum[w] = tsum;
    __syncthreads();
    if (t == 0) {
        float tot = wsum[0] + wsum[1] + wsum[2] + wsum[3];
        float sgn = ((ro < HALF) == (co < HALF)) ? 1.0f : -1.0f;
        float wgt = (bi == bj) ? 1.0f : 2.0f;       // off-diag tiles stand for (i,j)+(j,i)
        atomicAdd(accum, (double)(sgn * wgt * tot));
    }
}

// --- Finalize: mean normalization ---
__global__ void k_fin(const double* __restrict__ accum, float* __restrict__ out) {
    out[0] = (float)(*accum / ((double)HALF * (double)HALF));
}

extern "C" void kernel_launch(void* const* d_in, const int* in_sizes, int n_in,
                              void* d_out, int out_size, void* d_ws, size_t ws_size,
                              hipStream_t stream) {
    const float* src = (const float*)d_in[0];
    const float* tgt = (const float*)d_in[1];
    float* out = (float*)d_out;

    char* ws = (char*)d_ws;
    double* accum = (double*)ws;                                 // 8 B
    float*  scale = (float*)(ws + 16);                           // 4 B
    float*  sq    = (float*)(ws + 64);                           // 32768 B
    float*  part  = (float*)(ws + 64 + 32768);                   // 128*256*4 = 131072 B
    unsigned short* hi = (unsigned short*)(ws + 163904);         // 4 MB, 16B-aligned
    unsigned short* lo = (unsigned short*)(ws + 163904 + (size_t)NROWS * DIM * 2);

    k_conv <<<CONVB, 256, 0, stream>>>(src, tgt, hi, lo, sq, part, accum);
    k_scale<<<1, 256, 0, stream>>>(sq, part, scale);
    k_pairs<<<dim3(NROWS / BM, NROWS / BM), 256, 0, stream>>>(hi, lo, sq, scale, accum);
    k_fin  <<<1, 1, 0, stream>>>(accum, out);
}

// Round 7
// 147.655 us; speedup vs baseline: 1.7631x; 1.0074x over previous
//
#include <hip/hip_runtime.h>

// MMD loss, N=4096 per side, D=256, fp32.
// R7: split-bf16 MFMA Gram (hh+hl+lh; ll dropped, ~2^-17 rel), hi/lo planes in
//     DMA-native tiled layout (R6). KEY CHANGE: k_pairs has NO LDS / NO BARRIERS
//     in the K-loop — fragments are loaded straight global->VGPR (the tiled
//     layout makes each 64-lane fragment load 4x256B contiguous = 8 full cache
//     lines). Inter-wave reuse via L2: 1D grid of exactly 2080 upper-tri tiles,
//     band-of-8-columns decode keeps the in-flight working set ~2.5 MB < 4 MB
//     per-XCD L2. Compiler pipelines loads across unrolled k-steps with
//     fine-grained vmcnt(N) — impossible in the 2-barrier LDS structure (R6
//     plateau: MfmaUtil 28%, pipes idle on barrier drains).
//     __launch_bounds__(256,2): no forced occupancy -> no spills (R2 lesson).

#define NROWS 8192
#define HALF  4096
#define DIM   256
#define BM    128
#define CONVB 256         // k_conv blocks; 32 rows each (quarter panel)

typedef __bf16 bf16x8 __attribute__((ext_vector_type(8)));
typedef float f32x4 __attribute__((ext_vector_type(4)));
typedef unsigned short ushort8 __attribute__((ext_vector_type(8)));

__device__ __forceinline__ const float* row_ptr(const float* src, const float* tgt, int r) {
    return (r < HALF) ? (src + (size_t)r * DIM) : (tgt + (size_t)(r - HALF) * DIM);
}

__device__ __forceinline__ unsigned short bf16_rne(float x) {
    unsigned int u = __builtin_bit_cast(unsigned int, x);
    return (unsigned short)((u + 0x7FFFu + ((u >> 16) & 1u)) >> 16);
}

// --- Phase 0: fp32 -> hi/lo planes (tiled layout) + sq[] + colsum partials ---
// Tiled plane layout: 16B-granule index of (global row R, k-granule g) =
//   (R>>7)*4096 + g*128 + (R&127)        [panel-major, granule-major inside]
__global__ __launch_bounds__(256) void k_conv(const float* __restrict__ src,
                                              const float* __restrict__ tgt,
                                              unsigned short* __restrict__ hi,
                                              unsigned short* __restrict__ lo,
                                              float* __restrict__ sq,
                                              float* __restrict__ part,
                                              double* __restrict__ accum) {
    // LDS granule-major for this block's 32 rows: (g*32 + r) in 16B units
    __shared__ __align__(16) unsigned short sh_hi[32 * 32 * 8];  // 16 KB
    __shared__ __align__(16) unsigned short sh_lo[32 * 32 * 8];  // 16 KB
    __shared__ float4 cs[4][64];

    int w = threadIdx.x >> 6, lane = threadIdx.x & 63;
    int r0 = blockIdx.x * 32;                       // 32 rows per block
    int g  = lane >> 1, j = lane & 1;               // lane's float4 = half-granule
    float4 csum = {0.f, 0.f, 0.f, 0.f};
    #pragma unroll
    for (int i = 0; i < 8; ++i) {
        int rl  = w * 8 + i;                        // local row 0..31
        int row = r0 + rl;
        const float* rp = row_ptr(src, tgt, row);
        float4 v = ((const float4*)rp)[lane];       // coalesced: 64 lanes * 16 B
        float xs[4] = {v.x, v.y, v.z, v.w};
        unsigned short hs[4], ls[4];
        #pragma unroll
        for (int k = 0; k < 4; ++k) {
            unsigned short hh = bf16_rne(xs[k]);
            float hr = __builtin_bit_cast(float, (unsigned int)hh << 16);
            hs[k] = hh;
            ls[k] = bf16_rne(xs[k] - hr);
        }
        ushort4 h4 = {hs[0], hs[1], hs[2], hs[3]};
        ushort4 l4 = {ls[0], ls[1], ls[2], ls[3]};
        int so = (g * 32 + rl) * 8 + j * 4;
        *(ushort4*)&sh_hi[so] = h4;
        *(ushort4*)&sh_lo[so] = l4;
        csum.x += v.x; csum.y += v.y; csum.z += v.z; csum.w += v.w;
        float s = v.x * v.x + v.y * v.y + v.z * v.z + v.w * v.w;
        #pragma unroll
        for (int off = 32; off; off >>= 1) s += __shfl_xor(s, off, 64);
        if (lane == 0) sq[row] = s;
    }
    __syncthreads();
    // Coalesced tiled write-out: 1024 chunks of 16 B per plane.
    int panel = blockIdx.x >> 2, quarter = blockIdx.x & 3;
    #pragma unroll
    for (int c = threadIdx.x; c < 1024; c += 256) {
        int gg = c >> 5, r = c & 31;
        size_t goff = (((size_t)panel * 32 + gg) * 128 + quarter * 32 + r) * 8;
        *(ushort8*)&hi[goff] = *(const ushort8*)&sh_hi[c * 8];
        *(ushort8*)&lo[goff] = *(const ushort8*)&sh_lo[c * 8];
    }
    // colsum partials
    cs[w][lane] = csum;
    __syncthreads();
    if (w == 0) {
        float4 a = cs[0][lane], b = cs[1][lane], c = cs[2][lane], d = cs[3][lane];
        float4 tot = {a.x + b.x + c.x + d.x, a.y + b.y + c.y + d.y,
                      a.z + b.z + c.z + d.z, a.w + b.w + c.w + d.w};
        *(float4*)&part[(size_t)blockIdx.x * DIM + lane * 4] = tot;
    }
    if (blockIdx.x == 0 && threadIdx.x == 0) *accum = 0.0;
}

// --- Phase 1: bandwidth -> exp2 scale factor ---
__global__ __launch_bounds__(256) void k_scale(const float* __restrict__ sq,
                                               const float* __restrict__ part,
                                               float* __restrict__ scale) {
    __shared__ double sh[256];
    int t = threadIdx.x;
    double s1 = 0.0;
    for (int i = t; i < NROWS; i += 256) s1 += (double)sq[i];
    sh[t] = s1;
    __syncthreads();
    for (int off = 128; off; off >>= 1) {
        if (t < off) sh[t] += sh[t + off];
        __syncthreads();
    }
    double S1 = sh[0];
    __syncthreads();
    float c = 0.0f;
    for (int b = 0; b < CONVB; ++b) c += part[b * DIM + t];  // coalesced
    sh[t] = (double)c * (double)c;
    __syncthreads();
    for (int off = 128; off; off >>= 1) {
        if (t < off) sh[t] += sh[t + off];
        __syncthreads();
    }
    if (t == 0) {
        double S2    = sh[0];
        double n     = (double)NROWS;
        double sumL2 = 2.0 * n * S1 - 2.0 * S2;
        double bw    = sumL2 / (n * n - n) / 4.0;   // / KERNEL_MUL^(KERNEL_NUM//2)
        // u = exp(-L2/(16*bw)) = exp2(scale * L2)
        *scale = (float)(-1.0 / (16.0 * bw * 0.69314718055994530942));
    }
}

// --- Phase 2: barrier-free split-bf16 MFMA pair-tile kernel ---
__global__ __launch_bounds__(256, 2) void k_pairs(const unsigned short* __restrict__ hi,
                                                  const unsigned short* __restrict__ lo,
                                                  const float* __restrict__ sq,
                                                  const float* __restrict__ scale_p,
                                                  double* __restrict__ accum) {
    // Band decode: band k = bj/8; within band, bi-major, 8 consecutive columns.
    // Keeps the dispatch-consecutive working set ~2.5 MB (fits per-XCD L2).
    int id = blockIdx.x;
    int k = 0;
    while (k < 7 && 32 * (k + 1) * (k + 1) + 4 * (k + 1) <= id) ++k;
    int rem = id - (32 * k * k + 4 * k);
    int bi, col;
    if (rem < 64 * k) {                             // full rows (bi < 8k)
        bi = rem >> 3; col = rem & 7;
    } else {                                        // diagonal 8x8 corner
        int r2 = rem - 64 * k;
        int jj = 0, c = 0;
        while (c + (8 - jj) <= r2) { c += (8 - jj); ++jj; }
        bi = 8 * k + jj; col = jj + (r2 - c);
    }
    int bj = 8 * k + col;

    __shared__ float wsum[4];

    int t    = threadIdx.x;
    int lane = t & 63;
    int w    = t >> 6;
    int wr   = w >> 1, wc = w & 1;                  // 2x2 wave grid, 64x64 each
    int lr   = lane & 15, lq = lane >> 4;
    int ro = bi * BM, co = bj * BM;

    // Fragment bases in 16B-granule units within the tiled planes.
    size_t aBase = (size_t)bi * 4096 + lq * 128 + wr * 64 + lr;
    size_t bBase = (size_t)bj * 4096 + lq * 128 + wc * 64 + lr;
    const ushort8* pAh = (const ushort8*)hi + aBase;
    const ushort8* pAl = (const ushort8*)lo + aBase;
    const ushort8* pBh = (const ushort8*)hi + bBase;
    const ushort8* pBl = (const ushort8*)lo + bBase;

    f32x4 acc[4][4];
    #pragma unroll
    for (int m = 0; m < 4; ++m)
        #pragma unroll
        for (int n = 0; n < 4; ++n) acc[m][n] = (f32x4){0.f, 0.f, 0.f, 0.f};

    #pragma unroll
    for (int it = 0; it < DIM / 32; ++it) {
        // 16 coalesced global loads (4 x 256B contiguous segments each);
        // no barrier — compiler pipelines across iterations with vmcnt(N).
        bf16x8 aH[4], aL[4], bH[4], bL[4];
        #pragma unroll
        for (int m = 0; m < 4; ++m) {
            aH[m] = __builtin_bit_cast(bf16x8, pAh[it * 512 + m * 16]);
            aL[m] = __builtin_bit_cast(bf16x8, pAl[it * 512 + m * 16]);
        }
        #pragma unroll
        for (int n = 0; n < 4; ++n) {
            bH[n] = __builtin_bit_cast(bf16x8, pBh[it * 512 + n * 16]);
            bL[n] = __builtin_bit_cast(bf16x8, pBl[it * 512 + n * 16]);
        }
        #pragma unroll
        for (int m = 0; m < 4; ++m)
            #pragma unroll
            for (int n = 0; n < 4; ++n) {
                acc[m][n] = __builtin_amdgcn_mfma_f32_16x16x32_bf16(aH[m], bH[n], acc[m][n], 0, 0, 0);
                acc[m][n] = __builtin_amdgcn_mfma_f32_16x16x32_bf16(aH[m], bL[n], acc[m][n], 0, 0, 0);
                acc[m][n] = __builtin_amdgcn_mfma_f32_16x16x32_bf16(aL[m], bH[n], acc[m][n], 0, 0, 0);
                // lo*lo pass dropped: ~2^-17 relative on Gram term
            }
    }

    // ---- epilogue: L2 -> sum of 5 Gaussian kernels -> reduce
    float scale = *scale_p;
    int ro_eff = ro + wr * 64, co_eff = co + wc * 64;
    float4 sqa4[4];
    float  sqbv[4];
    #pragma unroll
    for (int m = 0; m < 4; ++m) sqa4[m] = *(const float4*)&sq[ro_eff + m * 16 + lq * 4];
    #pragma unroll
    for (int n = 0; n < 4; ++n) sqbv[n] = sq[co_eff + n * 16 + lr];

    float tsum = 0.0f;
    #pragma unroll
    for (int m = 0; m < 4; ++m) {
        float sa[4] = {sqa4[m].x, sqa4[m].y, sqa4[m].z, sqa4[m].w};
        #pragma unroll
        for (int n = 0; n < 4; ++n) {
            #pragma unroll
            for (int r = 0; r < 4; ++r) {
                float L2  = sa[r] + sqbv[n] - 2.0f * acc[m][n][r];
                float u   = __builtin_amdgcn_exp2f(scale * L2);
                float u2  = u * u;
                float u4  = u2 * u2;
                float u8  = u4 * u4;
                float u16 = u8 * u8;
                tsum += u + u2 + u4 + u8 + u16;     // 5 kernel scales
            }
        }
    }

    #pragma unroll
    for (int off = 32; off; off >>= 1) tsum += __shfl_xor(tsum, off, 64);
    if (lane == 0) wsum[w] = tsum;
    __syncthreads();
    if (t == 0) {
        float tot = wsum[0] + wsum[1] + wsum[2] + wsum[3];
        float sgn = ((ro < HALF) == (co < HALF)) ? 1.0f : -1.0f;
        float wgt = (bi == bj) ? 1.0f : 2.0f;       // off-diag tiles stand for (i,j)+(j,i)
        atomicAdd(accum, (double)(sgn * wgt * tot));
    }
}

// --- Finalize: mean normalization ---
__global__ void k_fin(const double* __restrict__ accum, float* __restrict__ out) {
    out[0] = (float)(*accum / ((double)HALF * (double)HALF));
}

extern "C" void kernel_launch(void* const* d_in, const int* in_sizes, int n_in,
                              void* d_out, int out_size, void* d_ws, size_t ws_size,
                              hipStream_t stream) {
    const float* src = (const float*)d_in[0];
    const float* tgt = (const float*)d_in[1];
    float* out = (float*)d_out;

    char* ws = (char*)d_ws;
    double* accum = (double*)ws;                                 // 8 B
    float*  scale = (float*)(ws + 16);                           // 4 B
    float*  sq    = (float*)(ws + 64);                           // 32768 B
    float*  part  = (float*)(ws + 64 + 32768);                   // 256*256*4 = 262144 B
    unsigned short* hi = (unsigned short*)(ws + 294976);         // 4 MB, 16B-aligned
    unsigned short* lo = (unsigned short*)(ws + 294976 + (size_t)NROWS * DIM * 2);

    k_conv <<<CONVB, 256, 0, stream>>>(src, tgt, hi, lo, sq, part, accum);
    k_scale<<<1, 256, 0, stream>>>(sq, part, scale);
    k_pairs<<<2080, 256, 0, stream>>>(hi, lo, sq, scale, accum);
    k_fin  <<<1, 1, 0, stream>>>(accum, out);
}